// Round 10
// baseline (829.257 us; speedup 1.0000x reference)
//
#include <hip/hip_runtime.h>
#include <cstdint>
#include <cstddef>

#define H_ 64
#define W_ 64
#define T_ 32
#define CIN_ 16
#define COUT_ 64
#define K_ 432
#define TH_ 4
#define TW_ 16
#define WR_ 6          // window rows: 4 + 2 halo
#define WC_ 24         // padded window cols (18 used)
#define WSZ_ (WR_ * WC_)     // 144
#define XTOT_ (CIN_ * WSZ_)  // 2304
#define NSLOT_ 3
#define NTHR_ 1024

// ---- prep: w_g[cout_grp][k][4] f32 (wave-contiguous), Gram d64, inv64 ----
__global__ void prep(const float* __restrict__ w, float* __restrict__ w_g,
                     double* __restrict__ d64, double* __restrict__ inv64) {
    const int i = blockIdx.x;   // cout row
    const int j = threadIdx.x;  // 0..63
    const float* wi = w + i * K_;
    const float* wj = w + j * K_;
    double acc = 0.0;
    for (int k = 0; k < K_; ++k) acc += (double)wi[k] * (double)wj[k];
    d64[i * 64 + j] = acc;
    if (i == j) inv64[i] = 1.0 / (acc + 1e-8);
    // grouped layout: w_g[(g*K_ + k)*4 + (cout&3)], g = cout>>2
    for (int k = j; k < K_; k += 64)
        w_g[(((i >> 2) * K_) + k) * 4 + (i & 3)] = wi[k];
}

// ---- fused conv3d + spiking recurrence (LDS-resident weights) ----
__launch_bounds__(NTHR_, 1)
__global__ void fused_snn(const float* __restrict__ xg,
                          const float* __restrict__ beta_g, const float* __restrict__ bias_g,
                          const float* __restrict__ w_g, const double* __restrict__ d64,
                          const double* __restrict__ inv64, float* __restrict__ out) {
    __shared__ __align__(16) float w_lds[COUT_ * K_];       // 110592 B
    __shared__ __align__(16) float x_win[NSLOT_ * XTOT_];   // 27648 B
    __shared__ __align__(16) float d_lds[64 * 65];          // 16640 B (fp32, padded rows)
    __shared__ unsigned int masks[2][64][2];                // 1024 B
    // total 155904 B < 160 KiB

    const int tid = threadIdx.x;
    const int b   = blockIdx.x;          // batch 0..3
    const int ty0 = blockIdx.y * TH_;
    const int tx0 = blockIdx.z * TW_;

    const int wv   = __builtin_amdgcn_readfirstlane(tid >> 6);  // wave 0..15
    const int lane = tid & 63;
    const int py   = lane >> 4;          // 0..3
    const int px   = lane & 15;          // 0..15
    const int c0   = wv * 4;             // wave owns couts [c0, c0+4)
    const int xoff = py * WC_ + px;

    // wave's contiguous LDS weight chunk (6912 B); uniform addr -> broadcast reads
    const float* wbase = w_lds + wv * (K_ * 4);

    // one-time staging: weights -> LDS (float4), d (fp32) -> LDS
    for (int i = tid; i < COUT_ * K_ / 4; i += NTHR_)
        reinterpret_cast<float4*>(w_lds)[i] = reinterpret_cast<const float4*>(w_g)[i];
    for (int i = tid; i < 4096; i += NTHR_)
        d_lds[(i >> 6) * 65 + (i & 63)] = (float)d64[i];
    if (tid < 128) masks[1][tid >> 1][tid & 1] = 0u;  // rbuf for t=0

    // stage slices z=0,1 into slots 0,1
    for (int z = 0; z < 2; ++z) {
        for (int i = tid; i < XTOT_; i += NTHR_) {
            int cin = i / WSZ_;
            int r2  = i - cin * WSZ_;
            int yy  = r2 / WC_;
            int xx  = r2 - yy * WC_;
            if (xx >= TW_ + 2) continue;        // pad cols never read
            int gy = ty0 - 1 + yy, gx = tx0 - 1 + xx;
            float v = 0.f;
            if (gy >= 0 && gy < H_ && gx >= 0 && gx < W_)
                v = xg[((size_t)(b * CIN_ + cin) * T_ + z) * (H_ * W_) + gy * W_ + gx];
            x_win[z * XTOT_ + i] = v;
        }
    }

    const double beta = (double)beta_g[0];
    const double omb  = 1.0 - beta;
    double inv_[4], bb[4];
#pragma unroll
    for (int ci = 0; ci < 4; ++ci) {
        inv_[ci] = inv64[c0 + ci];
        bb[ci]   = (double)bias_g[c0 + ci];
    }
    double mem[4];
#pragma unroll
    for (int ci = 0; ci < 4; ++ci) mem[ci] = 0.0;

    // prefetch/staging index precompute (3 elems max per thread)
    int  pf_loff[3];
    size_t pf_goff[3];
    bool pf_use[3], pf_in[3];
#pragma unroll
    for (int r = 0; r < 3; ++r) {
        int i = tid + r * NTHR_;
        int cin = i / WSZ_;
        int r2  = i - cin * WSZ_;
        int yy  = r2 / WC_;
        int xx  = r2 - yy * WC_;
        pf_loff[r] = i;
        int gy = ty0 - 1 + yy, gx = tx0 - 1 + xx;
        bool ok = (i < XTOT_) && (xx < TW_ + 2);
        pf_use[r] = ok;
        pf_in[r]  = ok && gy >= 0 && gy < H_ && gx >= 0 && gx < W_;
        pf_goff[r] = (size_t)(b * CIN_ + cin) * (T_ * H_ * W_) + (size_t)gy * W_ + gx;
    }

    for (int t = 0; t < T_; ++t) {
        __syncthreads();   // A: prev LDS writes + prev mask ORs visible
        if (tid < 128) masks[t & 1][tid >> 1][tid & 1] = 0u;  // clear wbuf

        // prefetch slice z=t+2 into regs (hidden under conv)
        float R[3];
        const int zp = t + 2;
        if (zp < T_) {
#pragma unroll
            for (int r = 0; r < 3; ++r) {
                R[r] = 0.f;
                if (pf_in[r]) R[r] = xg[pf_goff[r] + (size_t)zp * (H_ * W_)];
            }
        }

        // ---- conv: fp32 products, per-cin fp64 accumulate (R8 schedule) ----
        double accd[4];
#pragma unroll
        for (int ci = 0; ci < 4; ++ci) accd[ci] = 0.0;

        int slot_[3]; bool zok[3];
#pragma unroll
        for (int dz = 0; dz < 3; ++dz) {
            int z = t - 1 + dz;
            zok[dz]  = (z >= 0 && z < T_);
            slot_[dz] = zok[dz] ? (z % 3) : 0;
        }

        for (int cin = 0; cin < CIN_; ++cin) {
            // batch ALL x reads for this cin first (one DS-latency exposure)
            float xv[3][9];
#pragma unroll
            for (int dz = 0; dz < 3; ++dz) {
                if (!zok[dz]) continue;
                const float* xs = &x_win[slot_[dz] * XTOT_ + cin * WSZ_] + xoff;
#pragma unroll
                for (int dy = 0; dy < 3; ++dy) {
                    xv[dz][dy * 3 + 0] = xs[dy * WC_ + 0];
                    xv[dz][dy * 3 + 1] = xs[dy * WC_ + 1];
                    xv[dz][dy * 3 + 2] = xs[dy * WC_ + 2];
                }
            }
            float cacc[4];
#pragma unroll
            for (int ci = 0; ci < 4; ++ci) cacc[ci] = 0.f;
#pragma unroll
            for (int dz = 0; dz < 3; ++dz) {
                if (!zok[dz]) continue;
                // contiguous 144B LDS weight plane for this (cin,dz), uniform addr
                const float* wp = wbase + (cin * 27 + dz * 9) * 4;
#pragma unroll
                for (int dy = 0; dy < 3; ++dy) {
                    const float4 w0 = *reinterpret_cast<const float4*>(wp + (dy * 3 + 0) * 4);
                    const float4 w1 = *reinterpret_cast<const float4*>(wp + (dy * 3 + 1) * 4);
                    const float4 w2 = *reinterpret_cast<const float4*>(wp + (dy * 3 + 2) * 4);
                    const float xv0 = xv[dz][dy * 3 + 0];
                    const float xv1 = xv[dz][dy * 3 + 1];
                    const float xv2 = xv[dz][dy * 3 + 2];
                    cacc[0] = fmaf(w0.x, xv0, cacc[0]);
                    cacc[1] = fmaf(w0.y, xv0, cacc[1]);
                    cacc[2] = fmaf(w0.z, xv0, cacc[2]);
                    cacc[3] = fmaf(w0.w, xv0, cacc[3]);
                    cacc[0] = fmaf(w1.x, xv1, cacc[0]);
                    cacc[1] = fmaf(w1.y, xv1, cacc[1]);
                    cacc[2] = fmaf(w1.z, xv1, cacc[2]);
                    cacc[3] = fmaf(w1.w, xv1, cacc[3]);
                    cacc[0] = fmaf(w2.x, xv2, cacc[0]);
                    cacc[1] = fmaf(w2.y, xv2, cacc[1]);
                    cacc[2] = fmaf(w2.z, xv2, cacc[2]);
                    cacc[3] = fmaf(w2.w, xv2, cacc[3]);
                }
            }
#pragma unroll
            for (int ci = 0; ci < 4; ++ci) accd[ci] += (double)cacc[ci];
        }

        // ---- rst from previous spikes (sparse via bitmask), fp32 d, fp64 sum ----
        double rstv[4];
#pragma unroll
        for (int ci = 0; ci < 4; ++ci) rstv[ci] = 0.0;
        const int rb = (t + 1) & 1;
#pragma unroll
        for (int wrd = 0; wrd < 2; ++wrd) {
            unsigned int m = masks[rb][lane][wrd];
            while (m) {
                int bit = __ffs(m) - 1;
                m &= m - 1;
                const float* drow = &d_lds[(wrd * 32 + bit) * 65 + c0];
#pragma unroll
                for (int ci = 0; ci < 4; ++ci) rstv[ci] += (double)drow[ci];
            }
        }

        // ---- membrane update, spike, store ----
        unsigned int nib = 0u;
        const size_t obase = ((size_t)(b * COUT_ + c0) * T_ + t) * (size_t)(H_ * W_)
                           + (size_t)(ty0 + py) * W_ + (tx0 + px);
#pragma unroll
        for (int ci = 0; ci < 4; ++ci) {
            mem[ci] = (mem[ci] - rstv[ci]) * beta + accd[ci] * omb;
            const double mthr = mem[ci] * inv_[ci] - bb[ci];
            const int s = mthr > 0.0 ? 1 : 0;
            out[obase + (size_t)ci * (T_ * H_ * W_)] = (float)s;
            nib |= (unsigned int)s << ci;
        }

        __syncthreads();   // B: all clears + conv reads done before ORs / x writes
        if (nib) atomicOr(&masks[t & 1][lane][wv >> 3], nib << ((wv & 7) * 4));

        // write prefetched slice z=t+2 into slot (t+2)%3 (occupant z=t-2, done)
        if (zp < T_) {
            const int so = (zp % 3) * XTOT_;
#pragma unroll
            for (int r = 0; r < 3; ++r)
                if (pf_use[r]) x_win[so + pf_loff[r]] = R[r];
        }
    }
}

extern "C" void kernel_launch(void* const* d_in, const int* in_sizes, int n_in,
                              void* d_out, int out_size, void* d_ws, size_t ws_size,
                              hipStream_t stream) {
    const float* x    = (const float*)d_in[0];
    const float* w    = (const float*)d_in[1];
    const float* beta = (const float*)d_in[2];
    const float* bias = (const float*)d_in[3];
    float* out = (float*)d_out;

    float*  w_g   = (float*)d_ws;                                   // 110592 B
    double* d64   = (double*)((char*)d_ws + 110592);                // 32768 B
    double* inv64 = (double*)((char*)d_ws + 110592 + 32768);        // 512 B

    prep<<<dim3(64), dim3(64), 0, stream>>>(w, w_g, d64, inv64);
    fused_snn<<<dim3(4, 16, 4), dim3(NTHR_), 0, stream>>>(x, beta, bias, w_g, d64, inv64, out);
}

// Round 15
// 514.774 us; speedup vs baseline: 1.6109x; 1.6109x over previous
//
#include <hip/hip_runtime.h>
#include <cstdint>
#include <cstddef>

#define H_ 64
#define W_ 64
#define T_ 32
#define CIN_ 16
#define COUT_ 64
#define K_ 432
#define TH_ 4
#define TW_ 16
#define WR_ 6          // window rows: 4 + 2 halo
#define WC_ 24         // padded window cols (18 used)
#define WSZ_ (WR_ * WC_)     // 144
#define XTOT_ (CIN_ * WSZ_)  // 2304
#define NSLOT_ 4
#define NTHR_ 1024

// ---- prep: w_g[cout_grp][k][4] f32 (wave-contiguous), Gram d64, inv64 ----
__global__ void prep(const float* __restrict__ w, float* __restrict__ w_g,
                     double* __restrict__ d64, double* __restrict__ inv64) {
    const int i = blockIdx.x;   // cout row
    const int j = threadIdx.x;  // 0..63
    const float* wi = w + i * K_;
    const float* wj = w + j * K_;
    double acc = 0.0;
    for (int k = 0; k < K_; ++k) acc += (double)wi[k] * (double)wj[k];
    d64[i * 64 + j] = acc;
    if (i == j) inv64[i] = 1.0 / (acc + 1e-8);
    // grouped layout: w_g[(g*K_ + k)*4 + (cout&3)], g = cout>>2
    for (int k = j; k < K_; k += 64)
        w_g[(((i >> 2) * K_) + k) * 4 + (i & 3)] = wi[k];
}

// ---- fused conv3d + spiking recurrence (R6 structure, grouped weights,
//      per-cin batched x loads) ----
__launch_bounds__(NTHR_, 1)
__global__ void fused_snn(const float* __restrict__ xg,
                          const float* __restrict__ beta_g, const float* __restrict__ bias_g,
                          const float* __restrict__ w_g, const double* __restrict__ d64,
                          const double* __restrict__ inv64, float* __restrict__ out) {
    __shared__ __align__(16) float x_win[NSLOT_ * XTOT_];   // 36864 B
    __shared__ __align__(16) double d_lds[64 * 65];         // 33280 B (padded rows)
    __shared__ unsigned int masks[2][64][2];                // 1024 B

    const int tid = threadIdx.x;
    const int b   = blockIdx.x;          // batch 0..3
    const int ty0 = blockIdx.y * TH_;
    const int tx0 = blockIdx.z * TW_;

    const int wv   = __builtin_amdgcn_readfirstlane(tid >> 6);  // wave 0..15
    const int lane = tid & 63;
    const int py   = lane >> 4;          // 0..3
    const int px   = lane & 15;          // 0..15
    const int c0   = wv * 4;             // wave owns couts [c0, c0+4)
    const int xoff = py * WC_ + px;

    // wave's contiguous weight stream (6912 B), wave-uniform -> s_load
    const float* wbase = w_g + (size_t)wv * (K_ * 4);

    for (int i = tid; i < 4096; i += NTHR_)
        d_lds[(i >> 6) * 65 + (i & 63)] = d64[i];
    if (tid < 128) masks[1][tid >> 1][tid & 1] = 0u;  // rbuf for t=0

    // stage slices z=0,1 into slots 0,1
    for (int z = 0; z < 2; ++z) {
        for (int i = tid; i < XTOT_; i += NTHR_) {
            int cin = i / WSZ_;
            int r2  = i - cin * WSZ_;
            int yy  = r2 / WC_;
            int xx  = r2 - yy * WC_;
            if (xx >= TW_ + 2) continue;        // pad cols never read
            int gy = ty0 - 1 + yy, gx = tx0 - 1 + xx;
            float v = 0.f;
            if (gy >= 0 && gy < H_ && gx >= 0 && gx < W_)
                v = xg[((size_t)(b * CIN_ + cin) * T_ + z) * (H_ * W_) + gy * W_ + gx];
            x_win[z * XTOT_ + i] = v;
        }
    }

    const double beta = (double)beta_g[0];
    const double omb  = 1.0 - beta;
    double inv_[4], bb[4];
#pragma unroll
    for (int ci = 0; ci < 4; ++ci) {
        inv_[ci] = inv64[c0 + ci];
        bb[ci]   = (double)bias_g[c0 + ci];
    }
    double mem[4];
#pragma unroll
    for (int ci = 0; ci < 4; ++ci) mem[ci] = 0.0;

    // prefetch/staging index precompute (3 elems max per thread)
    int  pf_loff[3];
    size_t pf_goff[3];
    bool pf_use[3], pf_in[3];
#pragma unroll
    for (int r = 0; r < 3; ++r) {
        int i = tid + r * NTHR_;
        int cin = i / WSZ_;
        int r2  = i - cin * WSZ_;
        int yy  = r2 / WC_;
        int xx  = r2 - yy * WC_;
        pf_loff[r] = i;
        int gy = ty0 - 1 + yy, gx = tx0 - 1 + xx;
        bool ok = (i < XTOT_) && (xx < TW_ + 2);
        pf_use[r] = ok;
        pf_in[r]  = ok && gy >= 0 && gy < H_ && gx >= 0 && gx < W_;
        pf_goff[r] = (size_t)(b * CIN_ + cin) * (T_ * H_ * W_) + (size_t)gy * W_ + gx;
    }

    for (int t = 0; t < T_; ++t) {
        __syncthreads();   // A: prev LDS writes + prev mask ORs visible
        if (tid < 128) masks[t & 1][tid >> 1][tid & 1] = 0u;  // clear wbuf

        // prefetch slice z=t+2 into regs (hidden under conv)
        float R[3];
        const int zp = t + 2;
        if (zp < T_) {
#pragma unroll
            for (int r = 0; r < 3; ++r) {
                R[r] = 0.f;
                if (pf_in[r]) R[r] = xg[pf_goff[r] + (size_t)zp * (H_ * W_)];
            }
        }

        // ---- conv: fp32 products, per-cin fp64 accumulate ----
        double accd[4];
#pragma unroll
        for (int ci = 0; ci < 4; ++ci) accd[ci] = 0.0;

        int slot_[3]; bool zok[3];
#pragma unroll
        for (int dz = 0; dz < 3; ++dz) {
            int z = t - 1 + dz;
            zok[dz]  = (z >= 0 && z < T_);
            slot_[dz] = zok[dz] ? (z & 3) : 0;
        }

        for (int cin = 0; cin < CIN_; ++cin) {
            // batch ALL x reads for this cin first (one DS-latency exposure)
            float xv[3][9];
#pragma unroll
            for (int dz = 0; dz < 3; ++dz) {
                if (!zok[dz]) continue;
                const float* xs = &x_win[slot_[dz] * XTOT_ + cin * WSZ_] + xoff;
#pragma unroll
                for (int dy = 0; dy < 3; ++dy) {
                    xv[dz][dy * 3 + 0] = xs[dy * WC_ + 0];
                    xv[dz][dy * 3 + 1] = xs[dy * WC_ + 1];
                    xv[dz][dy * 3 + 2] = xs[dy * WC_ + 2];
                }
            }
            float cacc[4];
#pragma unroll
            for (int ci = 0; ci < 4; ++ci) cacc[ci] = 0.f;
#pragma unroll
            for (int dz = 0; dz < 3; ++dz) {
                if (!zok[dz]) continue;
                // contiguous 144B weight plane for this (cin,dz)
                const float* wp = wbase + (cin * 27 + dz * 9) * 4;
#pragma unroll
                for (int dy = 0; dy < 3; ++dy) {
                    const float4 w0 = *reinterpret_cast<const float4*>(wp + (dy * 3 + 0) * 4);
                    const float4 w1 = *reinterpret_cast<const float4*>(wp + (dy * 3 + 1) * 4);
                    const float4 w2 = *reinterpret_cast<const float4*>(wp + (dy * 3 + 2) * 4);
                    const float xv0 = xv[dz][dy * 3 + 0];
                    const float xv1 = xv[dz][dy * 3 + 1];
                    const float xv2 = xv[dz][dy * 3 + 2];
                    cacc[0] = fmaf(w0.x, xv0, cacc[0]);
                    cacc[1] = fmaf(w0.y, xv0, cacc[1]);
                    cacc[2] = fmaf(w0.z, xv0, cacc[2]);
                    cacc[3] = fmaf(w0.w, xv0, cacc[3]);
                    cacc[0] = fmaf(w1.x, xv1, cacc[0]);
                    cacc[1] = fmaf(w1.y, xv1, cacc[1]);
                    cacc[2] = fmaf(w1.z, xv1, cacc[2]);
                    cacc[3] = fmaf(w1.w, xv1, cacc[3]);
                    cacc[0] = fmaf(w2.x, xv2, cacc[0]);
                    cacc[1] = fmaf(w2.y, xv2, cacc[1]);
                    cacc[2] = fmaf(w2.z, xv2, cacc[2]);
                    cacc[3] = fmaf(w2.w, xv2, cacc[3]);
                }
            }
#pragma unroll
            for (int ci = 0; ci < 4; ++ci) accd[ci] += (double)cacc[ci];
        }

        // ---- rst from previous spikes (sparse via bitmask), fp64 d ----
        double rstv[4];
#pragma unroll
        for (int ci = 0; ci < 4; ++ci) rstv[ci] = 0.0;
        const int rb = (t + 1) & 1;
#pragma unroll
        for (int wrd = 0; wrd < 2; ++wrd) {
            unsigned int m = masks[rb][lane][wrd];
            while (m) {
                int bit = __ffs(m) - 1;
                m &= m - 1;
                const double* drow = &d_lds[(wrd * 32 + bit) * 65 + c0];
#pragma unroll
                for (int ci = 0; ci < 4; ++ci) rstv[ci] += drow[ci];
            }
        }

        // ---- membrane update, spike, store ----
        unsigned int nib = 0u;
        const size_t obase = ((size_t)(b * COUT_ + c0) * T_ + t) * (size_t)(H_ * W_)
                           + (size_t)(ty0 + py) * W_ + (tx0 + px);
#pragma unroll
        for (int ci = 0; ci < 4; ++ci) {
            mem[ci] = (mem[ci] - rstv[ci]) * beta + accd[ci] * omb;
            const double mthr = mem[ci] * inv_[ci] - bb[ci];
            const int s = mthr > 0.0 ? 1 : 0;
            out[obase + (size_t)ci * (T_ * H_ * W_)] = (float)s;
            nib |= (unsigned int)s << ci;
        }

        __syncthreads();   // B: all clears + conv reads done before ORs / x writes
        if (nib) atomicOr(&masks[t & 1][lane][wv >> 3], nib << ((wv & 7) * 4));

        // write prefetched slice z=t+2 into slot (t+2)&3 (not read this iter)
        if (zp < T_) {
            const int so = (zp & 3) * XTOT_;
#pragma unroll
            for (int r = 0; r < 3; ++r)
                if (pf_use[r]) x_win[so + pf_loff[r]] = R[r];
        }
    }
}

extern "C" void kernel_launch(void* const* d_in, const int* in_sizes, int n_in,
                              void* d_out, int out_size, void* d_ws, size_t ws_size,
                              hipStream_t stream) {
    const float* x    = (const float*)d_in[0];
    const float* w    = (const float*)d_in[1];
    const float* beta = (const float*)d_in[2];
    const float* bias = (const float*)d_in[3];
    float* out = (float*)d_out;

    float*  w_g   = (float*)d_ws;                                   // 110592 B
    double* d64   = (double*)((char*)d_ws + 110592);                // 32768 B
    double* inv64 = (double*)((char*)d_ws + 110592 + 32768);        // 512 B

    prep<<<dim3(64), dim3(64), 0, stream>>>(w, w_g, d64, inv64);
    fused_snn<<<dim3(4, 16, 4), dim3(NTHR_), 0, stream>>>(x, beta, bias, w_g, d64, inv64, out);
}